// Round 9
// baseline (94.406 us; speedup 1.0000x reference)
//
#include <hip/hip_runtime.h>

#define N_NODES 4096
#define BATCH 128
#define SPLITK 16
#define KCHUNK (N_NODES / SPLITK)               // 256
#define GEMM_BLOCKS 1024                        // 4096 indep waves (4/block)
#define TRANS_BLOCKS (64 * 64)                  // 4096 64x64 tiles

typedef _Float16 f16x4 __attribute__((ext_vector_type(4)));
typedef _Float16 f16x8 __attribute__((ext_vector_type(8)));
typedef float f32x4 __attribute__((ext_vector_type(4)));

// fp8 connT if the HW cvt builtins exist; else bf16 connT.
#if defined(__has_builtin)
#if __has_builtin(__builtin_amdgcn_cvt_f32_fp8) && __has_builtin(__builtin_amdgcn_cvt_pk_fp8_f32)
#define CONN_FP8 1
#endif
#endif
#ifndef CONN_FP8
#define CONN_FP8 0
#endif

#if CONN_FP8
#define CONN_ELEM_BYTES 1
#define CONN_SCALE (1.0f / 256.0f)
#else
#define CONN_ELEM_BYTES 2
#define CONN_SCALE 1.0f
#endif

__device__ __forceinline__ void conn_store4(void* out, size_t off, float4 v) {
#if CONN_FP8
  unsigned int p = __builtin_amdgcn_cvt_pk_fp8_f32(v.x * 256.0f, v.y * 256.0f, 0, false);
  p = (unsigned int)__builtin_amdgcn_cvt_pk_fp8_f32(v.z * 256.0f, v.w * 256.0f, (int)p, true);
  *(unsigned int*)((unsigned char*)out + off) = p;
#else
  const unsigned int ux = __float_as_uint(v.x), uy = __float_as_uint(v.y);
  const unsigned int uz = __float_as_uint(v.z), uw = __float_as_uint(v.w);
  ushort4 u;
  u.x = (unsigned short)((ux + 0x7FFFu + ((ux >> 16) & 1u)) >> 16);  // RNE
  u.y = (unsigned short)((uy + 0x7FFFu + ((uy >> 16) & 1u)) >> 16);
  u.z = (unsigned short)((uz + 0x7FFFu + ((uz >> 16) & 1u)) >> 16);
  u.w = (unsigned short)((uw + 0x7FFFu + ((uw >> 16) & 1u)) >> 16);
  *(ushort4*)((unsigned short*)out + off) = u;
#endif
}

__device__ __forceinline__ float4 conn_load4(const void* cT, int j, int t) {
#if CONN_FP8
  const unsigned int c = *(const unsigned int*)((const unsigned char*)cT + ((size_t)j << 12) + t * 4);
  return make_float4(__builtin_amdgcn_cvt_f32_fp8(c, 0), __builtin_amdgcn_cvt_f32_fp8(c, 1),
                     __builtin_amdgcn_cvt_f32_fp8(c, 2), __builtin_amdgcn_cvt_f32_fp8(c, 3));
#else
  const ushort4 c = *(const ushort4*)((const unsigned short*)cT + ((size_t)j << 12) + t * 4);
  return make_float4(__uint_as_float((unsigned int)c.x << 16),
                     __uint_as_float((unsigned int)c.y << 16),
                     __uint_as_float((unsigned int)c.z << 16),
                     __uint_as_float((unsigned int)c.w << 16));
#endif
}

// ---------------------------------------------------------------------------
// A-split: Ah/Al[128][4096] f16 planes, pre-scaled x256. Also zeroes maxslot.
// ---------------------------------------------------------------------------
__global__ __launch_bounds__(256) void asplit_kernel(const float* __restrict__ in,
                                                     _Float16* __restrict__ Ah,
                                                     _Float16* __restrict__ Al,
                                                     unsigned int* __restrict__ maxslot) {
  if (blockIdx.x == 0 && threadIdx.x == 0) *maxslot = 0u;
  const size_t idx = ((size_t)blockIdx.x * 256 + threadIdx.x) * 4;
  const float4 v = *(const float4*)(in + idx);
  f16x4 hi, lo;
  const float x0 = v.x * 256.f, x1 = v.y * 256.f, x2 = v.z * 256.f, x3 = v.w * 256.f;
  hi[0] = (_Float16)x0; lo[0] = (_Float16)(x0 - (float)hi[0]);
  hi[1] = (_Float16)x1; lo[1] = (_Float16)(x1 - (float)hi[1]);
  hi[2] = (_Float16)x2; lo[2] = (_Float16)(x2 - (float)hi[2]);
  hi[3] = (_Float16)x3; lo[3] = (_Float16)(x3 - (float)hi[3]);
  *(f16x4*)(Ah + idx) = hi;
  *(f16x4*)(Al + idx) = lo;
}

// ---------------------------------------------------------------------------
// Fused: blocks [0,1024) = barrier-free MFMA GEMM, fragments loaded DIRECTLY
// from global (no LDS, no staging, no barriers — each wave an independent
// 64x32 tile; A from pre-split f16 planes, W f32 split consumer-side).
// Blocks [1024, +4096) = connT transpose.
// P[s][m][n] = sum_{k in chunk s} A[m][k]*W[n][k] via Ah*Bh + Ah*Bl + Al*Bh.
// ---------------------------------------------------------------------------
struct TransSmem { float tile[64][65]; };

__global__ __launch_bounds__(256) void fused_prep_kernel(
    const _Float16* __restrict__ Ah, const _Float16* __restrict__ Al,
    const float* __restrict__ W, const float* __restrict__ conn,
    float* __restrict__ P, void* __restrict__ connT) {
  __shared__ TransSmem sm;
  const int tid = threadIdx.x;
  const int bid = blockIdx.x;

  if (bid < GEMM_BLOCKS) {
    // ---------------- GEMM role: one independent wave = one 64x32 tile -----
    const int wave = tid >> 6, lane = tid & 63;
    const int g = lane >> 4, lrow = lane & 15;  // frag lane coords
    const int w = (bid << 2) + wave;            // 0..4095
    const int n0 = (w & 127) * 32;              // 128 n-tiles
    const int m0 = ((w >> 7) & 1) * 64;         // 2 m-tiles
    const int kb = (w >> 8) * KCHUNK;           // 16 k-chunks

    f32x4 acc[4][2] = {};

    const _Float16* Ahb = Ah + (size_t)(m0 + lrow) * N_NODES + kb + g * 8;
    const _Float16* Alb = Al + (size_t)(m0 + lrow) * N_NODES + kb + g * 8;
    const float* Wb0 = W + (size_t)(n0 + lrow) * N_NODES + kb + g * 8;
    const float* Wb1 = W + (size_t)(n0 + 16 + lrow) * N_NODES + kb + g * 8;

#pragma unroll
    for (int kk = 0; kk < KCHUNK / 32; ++kk) {
      const int ko = kk * 32;
      // B frags: 2 cols-groups x 8 f32 -> hi/lo f16 (scale x64), in registers
      f16x8 bh[2], bl[2];
#pragma unroll
      for (int bn = 0; bn < 2; ++bn) {
        const float* wp = (bn ? Wb1 : Wb0) + ko;
        const f32x4 b0 = *(const f32x4*)wp;
        const f32x4 b1 = *(const f32x4*)(wp + 4);
#pragma unroll
        for (int j = 0; j < 4; ++j) {
          const float x = b0[j] * 64.f;
          const _Float16 h = (_Float16)x;
          bh[bn][j] = h; bl[bn][j] = (_Float16)(x - (float)h);
          const float y = b1[j] * 64.f;
          const _Float16 h2 = (_Float16)y;
          bh[bn][4 + j] = h2; bl[bn][4 + j] = (_Float16)(y - (float)h2);
        }
      }
      // A frags: direct 16B f16 loads, 4 m-frags x 2 planes
#pragma unroll
      for (int fm = 0; fm < 4; ++fm) {
        const f16x8 ah = *(const f16x8*)(Ahb + (size_t)(fm * 16) * N_NODES + ko);
        const f16x8 al = *(const f16x8*)(Alb + (size_t)(fm * 16) * N_NODES + ko);
#pragma unroll
        for (int bn = 0; bn < 2; ++bn) {
          acc[fm][bn] = __builtin_amdgcn_mfma_f32_16x16x32_f16(ah, bh[bn], acc[fm][bn], 0, 0, 0);
          acc[fm][bn] = __builtin_amdgcn_mfma_f32_16x16x32_f16(ah, bl[bn], acc[fm][bn], 0, 0, 0);
          acc[fm][bn] = __builtin_amdgcn_mfma_f32_16x16x32_f16(al, bh[bn], acc[fm][bn], 0, 0, 0);
        }
      }
    }

    // epilogue: D row = (lane>>4)*4 + reg, col = lane&15 (HW-verified)
    constexpr float INV = 1.0f / 16384.0f;  // 1/(256*64)
    float* Pb = P + (size_t)(w >> 8) * BATCH * N_NODES;
#pragma unroll
    for (int fm = 0; fm < 4; ++fm)
#pragma unroll
      for (int bn = 0; bn < 2; ++bn) {
        const int n = n0 + bn * 16 + lrow;
#pragma unroll
        for (int reg = 0; reg < 4; ++reg) {
          const int m = m0 + fm * 16 + g * 4 + reg;
          Pb[(size_t)m * N_NODES + n] = acc[fm][bn][reg] * INV;
        }
      }
  } else {
    // ---------------- transpose role: connT[j][i] = enc(conn[i][j]) ----------
    const int idx = bid - GEMM_BLOCKS;
    const int bx = idx & 63, by = idx >> 6;  // 64x64 tile coords
    const int tx = tid & 15, ty = tid >> 4;  // 16 x 16
#pragma unroll
    for (int r = 0; r < 4; ++r) {
      const float4 v =
          *(const float4*)(conn + (size_t)(by * 64 + ty + 16 * r) * N_NODES + bx * 64 + tx * 4);
      sm.tile[ty + 16 * r][tx * 4 + 0] = v.x;
      sm.tile[ty + 16 * r][tx * 4 + 1] = v.y;
      sm.tile[ty + 16 * r][tx * 4 + 2] = v.z;
      sm.tile[ty + 16 * r][tx * 4 + 3] = v.w;
    }
    __syncthreads();
#pragma unroll
    for (int r = 0; r < 4; ++r) {
      const int orow = ty + 16 * r;
      float4 v;
      v.x = sm.tile[tx * 4 + 0][orow];
      v.y = sm.tile[tx * 4 + 1][orow];
      v.z = sm.tile[tx * 4 + 2][orow];
      v.w = sm.tile[tx * 4 + 3][orow];
      conn_store4(connT, (size_t)(bx * 64 + orow) * N_NODES + by * 64 + tx * 4, v);
    }
  }
}

// ---------------------------------------------------------------------------
// Fallback-only f32 VALU GEMM (no workspace)
// ---------------------------------------------------------------------------
__global__ __launch_bounds__(256) void proj_gemm_valu(const float* __restrict__ A,
                                                      const float* __restrict__ W,
                                                      float* __restrict__ P,
                                                      unsigned int* __restrict__ maxslot) {
  if (blockIdx.x == 0 && threadIdx.x == 0) *maxslot = 0u;
  __shared__ float As[16][132];
  __shared__ float Bs[16][68];
  const int tid = threadIdx.x;
  const int n0 = blockIdx.x * 64;
  const int tx = tid & 15, ty = tid >> 4;
  const int arow = tid >> 1, acol = (tid & 1) * 8;
  const int brow = tid >> 2, bcol = (tid & 3) * 4;
  float acc[2][4][4] = {};
  const float* Aptr = A + (size_t)arow * N_NODES + acol;
  const float* Wptr = W + (size_t)(n0 + brow) * N_NODES + bcol;
  for (int k0 = 0; k0 < N_NODES; k0 += 16) {
    const float4 a0 = *(const float4*)(Aptr + k0);
    const float4 a1 = *(const float4*)(Aptr + k0 + 4);
    const float4 bv = *(const float4*)(Wptr + k0);
    __syncthreads();
    As[acol + 0][arow] = a0.x; As[acol + 1][arow] = a0.y;
    As[acol + 2][arow] = a0.z; As[acol + 3][arow] = a0.w;
    As[acol + 4][arow] = a1.x; As[acol + 5][arow] = a1.y;
    As[acol + 6][arow] = a1.z; As[acol + 7][arow] = a1.w;
    Bs[bcol + 0][brow] = bv.x; Bs[bcol + 1][brow] = bv.y;
    Bs[bcol + 2][brow] = bv.z; Bs[bcol + 3][brow] = bv.w;
    __syncthreads();
#pragma unroll
    for (int kk = 0; kk < 16; ++kk) {
      const float4 av0 = *(const float4*)&As[kk][ty * 4];
      const float4 av1 = *(const float4*)&As[kk][64 + ty * 4];
      const float4 bv4 = *(const float4*)&Bs[kk][tx * 4];
      const float am[8] = {av0.x, av0.y, av0.z, av0.w, av1.x, av1.y, av1.z, av1.w};
      const float bn[4] = {bv4.x, bv4.y, bv4.z, bv4.w};
#pragma unroll
      for (int i2 = 0; i2 < 2; ++i2)
#pragma unroll
        for (int i = 0; i < 4; ++i)
#pragma unroll
          for (int j = 0; j < 4; ++j)
            acc[i2][i][j] += am[i2 * 4 + i] * bn[j];
    }
  }
#pragma unroll
  for (int i2 = 0; i2 < 2; ++i2)
#pragma unroll
    for (int i = 0; i < 4; ++i) {
      const int m = i2 * 64 + ty * 4 + i;
      *(float4*)(P + (size_t)m * N_NODES + n0 + tx * 4) =
          make_float4(acc[i2][i][0], acc[i2][i][1], acc[i2][i][2], acc[i2][i][3]);
    }
}

__global__ __launch_bounds__(256) void bias_inplace_kernel(float* __restrict__ P,
                                                           const float* __restrict__ bias) {
  const size_t base = ((size_t)blockIdx.x * 256 + threadIdx.x) * 4;
  const int n = (int)(base & (N_NODES - 1));
  float4 s = *(const float4*)(P + base);
  const float4 bv = *(const float4*)(bias + n);
  s.x += bv.x; s.y += bv.y; s.z += bv.z; s.w += bv.w;
  *(float4*)(P + base) = s;
}

// ---------------------------------------------------------------------------
// Avalanche: one workgroup per sample; state in registers.
// ---------------------------------------------------------------------------
template <int MODE, int NSPLIT>
__global__ __launch_bounds__(1024) void avalanche_kernel(const float* __restrict__ Pin,
                                                         const float* __restrict__ bias,
                                                         const void* __restrict__ connv,
                                                         float* __restrict__ out,
                                                         unsigned int* __restrict__ maxslot) {
  const int b = blockIdx.x;
  const int t = threadIdx.x;
  __shared__ unsigned long long mask[64];
  __shared__ int wincl[64];
  __shared__ int list[N_NODES];

  float4 s;
  if (MODE == 1) {
    const float4 bv = *(const float4*)(bias + t * 4);
    s = bv;
#pragma unroll
    for (int sp = 0; sp < NSPLIT; ++sp) {
      const float4 v = *(const float4*)(Pin + (size_t)sp * BATCH * N_NODES +
                                        (size_t)b * N_NODES + t * 4);
      s.x += v.x; s.y += v.y; s.z += v.z; s.w += v.w;
    }
  } else {
    s = *(const float4*)(Pin + (size_t)b * N_NODES + t * 4);
  }

  float total = 0.0f;

  for (int it = 0; it < 100; ++it) {
    const float v0 = s.x, v1 = s.y, v2 = s.z, v3 = s.w;
    unsigned int bits = 0;
    if (v0 > 1.0f) bits |= 1u;
    if (v1 > 1.0f) bits |= 2u;
    if (v2 > 1.0f) bits |= 4u;
    if (v3 > 1.0f) bits |= 8u;

    __syncthreads();
    if (t < 64) mask[t] = 0ULL;
    __syncthreads();
    if (bits) atomicOr(&mask[t >> 4], (unsigned long long)bits << ((t & 15) * 4));
    __syncthreads();

    if (t < 64) {
      int incl = __popcll(mask[t]);
#pragma unroll
      for (int d = 1; d < 64; d <<= 1) {
        const int y = __shfl_up(incl, d);
        if (t >= d) incl += y;
      }
      wincl[t] = incl;
    }
    __syncthreads();
    const int n = wincl[63];
    if (n == 0) break;  // sticky done: state frozen
    total += (float)n;

    if (t < 64) {
      unsigned long long m = mask[t];
      int o = wincl[t] - __popcll(m);
      while (m) {
        list[o++] = (t << 6) + __builtin_ctzll(m);
        m &= m - 1;
      }
    }
    __syncthreads();

    float4 a0 = make_float4(0.f, 0.f, 0.f, 0.f), a1 = a0, a2 = a0, a3 = a0;
    if (MODE == 1) {
      int idx = 0;
      for (; idx + 8 <= n; idx += 8) {
        const float4 c0 = conn_load4(connv, list[idx + 0], t);
        const float4 c1 = conn_load4(connv, list[idx + 1], t);
        const float4 c2 = conn_load4(connv, list[idx + 2], t);
        const float4 c3 = conn_load4(connv, list[idx + 3], t);
        const float4 c4 = conn_load4(connv, list[idx + 4], t);
        const float4 c5 = conn_load4(connv, list[idx + 5], t);
        const float4 c6 = conn_load4(connv, list[idx + 6], t);
        const float4 c7 = conn_load4(connv, list[idx + 7], t);
        a0.x += c0.x; a0.y += c0.y; a0.z += c0.z; a0.w += c0.w;
        a1.x += c1.x; a1.y += c1.y; a1.z += c1.z; a1.w += c1.w;
        a2.x += c2.x; a2.y += c2.y; a2.z += c2.z; a2.w += c2.w;
        a3.x += c3.x; a3.y += c3.y; a3.z += c3.z; a3.w += c3.w;
        a0.x += c4.x; a0.y += c4.y; a0.z += c4.z; a0.w += c4.w;
        a1.x += c5.x; a1.y += c5.y; a1.z += c5.z; a1.w += c5.w;
        a2.x += c6.x; a2.y += c6.y; a2.z += c6.z; a2.w += c6.w;
        a3.x += c7.x; a3.y += c7.y; a3.z += c7.z; a3.w += c7.w;
      }
      for (; idx < n; ++idx) {
        const float4 c = conn_load4(connv, list[idx], t);
        a0.x += c.x; a0.y += c.y; a0.z += c.z; a0.w += c.w;
      }
    } else {
      const float* conn = (const float*)connv;
      for (int idx = 0; idx < n; ++idx) {
        const int j = list[idx];
        a0.x += conn[(size_t)(t * 4 + 0) * N_NODES + j];
        a0.y += conn[(size_t)(t * 4 + 1) * N_NODES + j];
        a0.z += conn[(size_t)(t * 4 + 2) * N_NODES + j];
        a0.w += conn[(size_t)(t * 4 + 3) * N_NODES + j];
      }
    }
    const float sc = (MODE == 1) ? CONN_SCALE : 1.0f;
    const float4 acc = make_float4(((a0.x + a1.x) + (a2.x + a3.x)) * sc,
                                   ((a0.y + a1.y) + (a2.y + a3.y)) * sc,
                                   ((a0.z + a1.z) + (a2.z + a3.z)) * sc,
                                   ((a0.w + a1.w) + (a2.w + a3.w)) * sc);

    s.x = (v0 > 1.0f) ? 0.0f : 0.9f * v0 + acc.x;
    s.y = (v1 > 1.0f) ? 0.0f : 0.9f * v1 + acc.y;
    s.z = (v2 > 1.0f) ? 0.0f : 0.9f * v2 + acc.z;
    s.w = (v3 > 1.0f) ? 0.0f : 0.9f * v3 + acc.w;
  }

  *(float4*)(out + (size_t)b * N_NODES + t * 4) = s;
  if (t == 0) atomicMax(maxslot, __float_as_uint(total));  // totals >= 0
}

// ---------------------------------------------------------------------------
extern "C" void kernel_launch(void* const* d_in, const int* in_sizes, int n_in,
                              void* d_out, int out_size, void* d_ws, size_t ws_size,
                              hipStream_t stream) {
  const float* input = (const float*)d_in[0];  // [128,4096]
  const float* W     = (const float*)d_in[1];  // [4096,4096]
  const float* bias  = (const float*)d_in[2];  // [4096]
  const float* conn  = (const float*)d_in[3];  // [4096,4096]
  float* out = (float*)d_out;                  // [128*4096] state + [1] max_size

  const size_t aplane_bytes = (size_t)BATCH * N_NODES * 2;                       // 1 MB each
  const size_t connT_bytes  = (size_t)N_NODES * N_NODES * CONN_ELEM_BYTES;       // 16/32 MB
  const size_t part_bytes   = (size_t)SPLITK * BATCH * N_NODES * sizeof(float);  // 32 MB
  unsigned int* maxslot = (unsigned int*)(out + (size_t)BATCH * N_NODES);

  if (ws_size >= 2 * aplane_bytes + connT_bytes + part_bytes) {
    _Float16* Ah = (_Float16*)d_ws;
    _Float16* Al = (_Float16*)((char*)d_ws + aplane_bytes);
    void* connT  = (char*)d_ws + 2 * aplane_bytes;
    float* part  = (float*)((char*)d_ws + 2 * aplane_bytes + connT_bytes);
    asplit_kernel<<<BATCH * N_NODES / 1024, 256, 0, stream>>>(input, Ah, Al, maxslot);
    fused_prep_kernel<<<GEMM_BLOCKS + TRANS_BLOCKS, 256, 0, stream>>>(Ah, Al, W, conn, part,
                                                                      connT);
    avalanche_kernel<1, SPLITK><<<BATCH, 1024, 0, stream>>>(part, bias, connT, out, maxslot);
  } else {
    // Fallback: no workspace — f32 GEMM into d_out, in-place bias, strided gather.
    proj_gemm_valu<<<dim3(N_NODES / 64, 1), 256, 0, stream>>>(input, W, out, maxslot);
    bias_inplace_kernel<<<BATCH * N_NODES / 1024, 256, 0, stream>>>(out, bias);
    avalanche_kernel<0, 1><<<BATCH, 1024, 0, stream>>>(out, nullptr, conn, out, maxslot);
  }
}

// Round 10
// 70.167 us; speedup vs baseline: 1.3454x; 1.3454x over previous
//
#include <hip/hip_runtime.h>

#define N_NODES 4096
#define BATCH 128
#define SPLITK 8
#define GBN 32                     // GEMM N-tile
#define GBK 64                     // GEMM K-step (elems)
#define KCHUNK (N_NODES / SPLITK)  // 512
#define NSTEP (KCHUNK / GBK)       // 8
#define GEMM_BLOCKS ((N_NODES / GBN) * SPLITK)  // 1024
#define TRANS_BLOCKS 1024                       // 4 tiles/block, 1 wave/tile

typedef _Float16 f16x4 __attribute__((ext_vector_type(4)));
typedef _Float16 f16x8 __attribute__((ext_vector_type(8)));
typedef float f32x4 __attribute__((ext_vector_type(4)));
typedef unsigned int u32x4 __attribute__((ext_vector_type(4)));

// ---- async global->LDS DMA (dest = wave-uniform base + lane*16) ----
__device__ __forceinline__ void dma16(const void* g, void* l) {
#if defined(__has_builtin) && __has_builtin(__builtin_amdgcn_global_load_lds)
  __builtin_amdgcn_global_load_lds((const __attribute__((address_space(1))) void*)g,
                                   (__attribute__((address_space(3))) void*)l, 16, 0, 0);
#else
  *(u32x4*)l = *(const u32x4*)g;
#endif
}

// fp8 connT if the HW cvt builtins exist; else bf16 connT.
#if defined(__has_builtin)
#if __has_builtin(__builtin_amdgcn_cvt_f32_fp8) && __has_builtin(__builtin_amdgcn_cvt_pk_fp8_f32)
#define CONN_FP8 1
#endif
#endif
#ifndef CONN_FP8
#define CONN_FP8 0
#endif

#if CONN_FP8
#define CONN_ELEM_BYTES 1
#define CONN_SCALE (1.0f / 256.0f)
#else
#define CONN_ELEM_BYTES 2
#define CONN_SCALE 1.0f
#endif

__device__ __forceinline__ void conn_store4(void* out, size_t off, float4 v) {
#if CONN_FP8
  unsigned int p = __builtin_amdgcn_cvt_pk_fp8_f32(v.x * 256.0f, v.y * 256.0f, 0, false);
  p = (unsigned int)__builtin_amdgcn_cvt_pk_fp8_f32(v.z * 256.0f, v.w * 256.0f, (int)p, true);
  *(unsigned int*)((unsigned char*)out + off) = p;
#else
  const unsigned int ux = __float_as_uint(v.x), uy = __float_as_uint(v.y);
  const unsigned int uz = __float_as_uint(v.z), uw = __float_as_uint(v.w);
  ushort4 u;
  u.x = (unsigned short)((ux + 0x7FFFu + ((ux >> 16) & 1u)) >> 16);  // RNE
  u.y = (unsigned short)((uy + 0x7FFFu + ((uy >> 16) & 1u)) >> 16);
  u.z = (unsigned short)((uz + 0x7FFFu + ((uz >> 16) & 1u)) >> 16);
  u.w = (unsigned short)((uw + 0x7FFFu + ((uw >> 16) & 1u)) >> 16);
  *(ushort4*)((unsigned short*)out + off) = u;
#endif
}

__device__ __forceinline__ float4 conn_load4(const void* cT, int j, int t) {
#if CONN_FP8
  const unsigned int c = *(const unsigned int*)((const unsigned char*)cT + ((size_t)j << 12) + t * 4);
  return make_float4(__builtin_amdgcn_cvt_f32_fp8(c, 0), __builtin_amdgcn_cvt_f32_fp8(c, 1),
                     __builtin_amdgcn_cvt_f32_fp8(c, 2), __builtin_amdgcn_cvt_f32_fp8(c, 3));
#else
  const ushort4 c = *(const ushort4*)((const unsigned short*)cT + ((size_t)j << 12) + t * 4);
  return make_float4(__uint_as_float((unsigned int)c.x << 16),
                     __uint_as_float((unsigned int)c.y << 16),
                     __uint_as_float((unsigned int)c.z << 16),
                     __uint_as_float((unsigned int)c.w << 16));
#endif
}

// ---------------------------------------------------------------------------
// A-split: Ah/Al[128][4096] f16 planes, pre-scaled x256. Also zeroes maxslot.
// ---------------------------------------------------------------------------
__global__ __launch_bounds__(256) void asplit_kernel(const float* __restrict__ in,
                                                     _Float16* __restrict__ Ah,
                                                     _Float16* __restrict__ Al,
                                                     unsigned int* __restrict__ maxslot) {
  if (blockIdx.x == 0 && threadIdx.x == 0) *maxslot = 0u;
  const size_t idx = ((size_t)blockIdx.x * 256 + threadIdx.x) * 4;
  const float4 v = *(const float4*)(in + idx);
  f16x4 hi, lo;
  const float x0 = v.x * 256.f, x1 = v.y * 256.f, x2 = v.z * 256.f, x3 = v.w * 256.f;
  hi[0] = (_Float16)x0; lo[0] = (_Float16)(x0 - (float)hi[0]);
  hi[1] = (_Float16)x1; lo[1] = (_Float16)(x1 - (float)hi[1]);
  hi[2] = (_Float16)x2; lo[2] = (_Float16)(x2 - (float)hi[2]);
  hi[3] = (_Float16)x3; lo[3] = (_Float16)(x3 - (float)hi[3]);
  *(f16x4*)(Ah + idx) = hi;
  *(f16x4*)(Al + idx) = lo;
}

// ---------------------------------------------------------------------------
// Fused prep. Blocks [0,1024): T3/T4 GEMM — LDS dbuf + global_load_lds DMA +
// counted vmcnt (tile t+1 stays in flight across the barriers).
// Blocks [1024,2048): per-wave barrier-free transpose, 4 tiles/block.
// ---------------------------------------------------------------------------
struct GemmSmem {
  alignas(16) _Float16 Ah[2][128 * GBK];  // 2 x 16 KB
  alignas(16) _Float16 Al[2][128 * GBK];  // 2 x 16 KB
  alignas(16) float B[2][GBN * GBK];      // 2 x 8 KB
};  // 80 KB total -> 2 blocks/CU (gfx950 allows up to 160 KB/workgroup)
struct TransSmem { float tile[4][64][65]; };  // 66.6 KB
union PrepSmem { GemmSmem g; TransSmem t; };

__global__ __launch_bounds__(256, 2) void fused_prep_kernel(
    const _Float16* __restrict__ Ahp, const _Float16* __restrict__ Alp,
    const float* __restrict__ W, const float* __restrict__ conn,
    float* __restrict__ P, void* __restrict__ connT) {
  __shared__ PrepSmem sm;
  const int tid = threadIdx.x;
  const int bid = blockIdx.x;
  const int wave = tid >> 6, lane = tid & 63;

  if (bid < GEMM_BLOCKS) {
    // ---------------- GEMM role ----------------
    const int wm = wave >> 1, wn = wave & 1;    // 2x2 wave grid
    const int g = lane >> 4, lrow = lane & 15;  // frag lane coords
    const int n0 = (bid & 127) * GBN;
    const int kb = (bid >> 7) * KCHUNK;

    const char* AsrcBase = (const char*)((wave >> 1) ? Alp : Ahp);
    const int ac0 = (wave & 1) * 8;
    const int arow_l = lane >> 3;                                 // == row&7
    const int ainrow = (((lane & 7) << 4) ^ ((lane >> 3) << 4));  // swizzled src byte
    const int brow_l = lane >> 4;
    const int binrow0 = (lane & 15) << 4;

    // 10 DMAs per wave per issue (8 A-chunks + 2 B-chunks of 1 KB)
    auto issue = [&](int buf, int t) {
      const size_t kbyteA = (size_t)(kb + t * GBK) * 2;
      const size_t kbyteB = (size_t)(kb + t * GBK) * 4;
      char* AldsB = (char*)((wave >> 1) ? sm.g.Al[buf] : sm.g.Ah[buf]);
#pragma unroll
      for (int i = 0; i < 8; ++i) {
        const int c = ac0 + i;
        const int row = 8 * c + arow_l;
        dma16(AsrcBase + (size_t)row * (N_NODES * 2) + kbyteA + ainrow,
              AldsB + c * 1024 + lane * 16);
      }
#pragma unroll
      for (int i = 0; i < 2; ++i) {
        const int c = wave * 2 + i;
        const int row = 4 * c + brow_l;
        dma16((const char*)W + (size_t)(n0 + row) * (N_NODES * 4) + kbyteB +
                  (binrow0 ^ ((row & 7) << 4)),
              (char*)sm.g.B[buf] + c * 1024 + lane * 16);
      }
    };

    f32x4 acc[4] = {};
    issue(0, 0);
    issue(1, 1);

#pragma unroll
    for (int t = 0; t < NSTEP; ++t) {
      const int cur = t & 1;
      // Counted drain: only tile t's 10 DMAs must land; tile t+1 stays in flight.
      if (t + 1 < NSTEP) asm volatile("s_waitcnt vmcnt(10)" ::: "memory");
      else               asm volatile("s_waitcnt vmcnt(0)" ::: "memory");
      __builtin_amdgcn_sched_barrier(0);
      __builtin_amdgcn_s_barrier();
      __builtin_amdgcn_sched_barrier(0);

#pragma unroll
      for (int kk = 0; kk < 2; ++kk) {
        // B frag: 8 f32 (swizzled LDS) -> bh/bl split (x64), consumer-side
        const int br = wn * 16 + lrow;
        const char* bbase = (const char*)sm.g.B[cur] + br * 256;
        const int bm = (br & 7) << 4;
        const int cb = (kk * 32 + g * 8) * 4;
        const f32x4 b0 = *(const f32x4*)(bbase + ((cb) ^ bm));
        const f32x4 b1 = *(const f32x4*)(bbase + ((cb + 16) ^ bm));
        f16x8 bh, bl;
#pragma unroll
        for (int j = 0; j < 4; ++j) {
          const float x = b0[j] * 64.f;
          const _Float16 h = (_Float16)x;
          bh[j] = h; bl[j] = (_Float16)(x - (float)h);
          const float y = b1[j] * 64.f;
          const _Float16 h2 = (_Float16)y;
          bh[4 + j] = h2; bl[4 + j] = (_Float16)(y - (float)h2);
        }
#pragma unroll
        for (int fm = 0; fm < 4; ++fm) {
          const int ar = wm * 64 + fm * 16 + lrow;
          const int am = (ar & 7) << 4;
          const int ca = (kk * 32 + g * 8) * 2;
          const f16x8 ah = *(const f16x8*)((const char*)sm.g.Ah[cur] + ar * 128 + (ca ^ am));
          const f16x8 al = *(const f16x8*)((const char*)sm.g.Al[cur] + ar * 128 + (ca ^ am));
          acc[fm] = __builtin_amdgcn_mfma_f32_16x16x32_f16(ah, bh, acc[fm], 0, 0, 0);
          acc[fm] = __builtin_amdgcn_mfma_f32_16x16x32_f16(ah, bl, acc[fm], 0, 0, 0);
          acc[fm] = __builtin_amdgcn_mfma_f32_16x16x32_f16(al, bh, acc[fm], 0, 0, 0);
        }
      }

      __builtin_amdgcn_sched_barrier(0);
      __builtin_amdgcn_s_barrier();  // all waves done reading buf cur
      __builtin_amdgcn_sched_barrier(0);
      if (t + 2 < NSTEP) issue(cur, t + 2);  // refill just-freed buffer
    }

    // epilogue: D row = (lane>>4)*4 + reg, col = lane&15 (HW-verified)
    constexpr float INV = 1.0f / 16384.0f;  // 1/(256*64)
    float* Pb = P + (size_t)(bid >> 7) * BATCH * N_NODES;
    const int n = n0 + wn * 16 + lrow;
#pragma unroll
    for (int fm = 0; fm < 4; ++fm)
#pragma unroll
      for (int reg = 0; reg < 4; ++reg) {
        const int m = wm * 64 + fm * 16 + g * 4 + reg;
        Pb[(size_t)m * N_NODES + n] = acc[fm][reg] * INV;
      }
  } else {
    // -------- transpose role: per-wave, barrier-free, 4 tiles/block --------
    const int tile_id = (bid - GEMM_BLOCKS) * 4 + wave;  // 0..4095
    const int bx = tile_id & 63, by = tile_id >> 6;
    float (*T)[65] = sm.t.tile[wave];
    const int lr = lane >> 4;  // 0..3
    const int lc = lane & 15;  // 0..15
#pragma unroll
    for (int i = 0; i < 16; ++i) {
      const int r = lr + 4 * i;
      const float4 v = *(const float4*)(conn + (size_t)(by * 64 + r) * N_NODES + bx * 64 + lc * 4);
      T[r][lc * 4 + 0] = v.x; T[r][lc * 4 + 1] = v.y;
      T[r][lc * 4 + 2] = v.z; T[r][lc * 4 + 3] = v.w;
    }
    // same-wave LDS write->read: compiler inserts lgkmcnt; no barrier needed
#pragma unroll
    for (int i = 0; i < 16; ++i) {
      const int orow = lr + 4 * i;
      float4 v;
      v.x = T[lc * 4 + 0][orow];
      v.y = T[lc * 4 + 1][orow];
      v.z = T[lc * 4 + 2][orow];
      v.w = T[lc * 4 + 3][orow];
      conn_store4(connT, (size_t)(bx * 64 + orow) * N_NODES + by * 64 + lc * 4, v);
    }
  }
}

// ---------------------------------------------------------------------------
// Fallback-only f32 VALU GEMM (no workspace)
// ---------------------------------------------------------------------------
__global__ __launch_bounds__(256) void proj_gemm_valu(const float* __restrict__ A,
                                                      const float* __restrict__ W,
                                                      float* __restrict__ P,
                                                      unsigned int* __restrict__ maxslot) {
  if (blockIdx.x == 0 && threadIdx.x == 0) *maxslot = 0u;
  __shared__ float As[16][132];
  __shared__ float Bs[16][68];
  const int tid = threadIdx.x;
  const int n0 = blockIdx.x * 64;
  const int tx = tid & 15, ty = tid >> 4;
  const int arow = tid >> 1, acol = (tid & 1) * 8;
  const int brow = tid >> 2, bcol = (tid & 3) * 4;
  float acc[2][4][4] = {};
  const float* Aptr = A + (size_t)arow * N_NODES + acol;
  const float* Wptr = W + (size_t)(n0 + brow) * N_NODES + bcol;
  for (int k0 = 0; k0 < N_NODES; k0 += 16) {
    const float4 a0 = *(const float4*)(Aptr + k0);
    const float4 a1 = *(const float4*)(Aptr + k0 + 4);
    const float4 bv = *(const float4*)(Wptr + k0);
    __syncthreads();
    As[acol + 0][arow] = a0.x; As[acol + 1][arow] = a0.y;
    As[acol + 2][arow] = a0.z; As[acol + 3][arow] = a0.w;
    As[acol + 4][arow] = a1.x; As[acol + 5][arow] = a1.y;
    As[acol + 6][arow] = a1.z; As[acol + 7][arow] = a1.w;
    Bs[bcol + 0][brow] = bv.x; Bs[bcol + 1][brow] = bv.y;
    Bs[bcol + 2][brow] = bv.z; Bs[bcol + 3][brow] = bv.w;
    __syncthreads();
#pragma unroll
    for (int kk = 0; kk < 16; ++kk) {
      const float4 av0 = *(const float4*)&As[kk][ty * 4];
      const float4 av1 = *(const float4*)&As[kk][64 + ty * 4];
      const float4 bv4 = *(const float4*)&Bs[kk][tx * 4];
      const float am[8] = {av0.x, av0.y, av0.z, av0.w, av1.x, av1.y, av1.z, av1.w};
      const float bn[4] = {bv4.x, bv4.y, bv4.z, bv4.w};
#pragma unroll
      for (int i2 = 0; i2 < 2; ++i2)
#pragma unroll
        for (int i = 0; i < 4; ++i)
#pragma unroll
          for (int j = 0; j < 4; ++j)
            acc[i2][i][j] += am[i2 * 4 + i] * bn[j];
    }
  }
#pragma unroll
  for (int i2 = 0; i2 < 2; ++i2)
#pragma unroll
    for (int i = 0; i < 4; ++i) {
      const int m = i2 * 64 + ty * 4 + i;
      *(float4*)(P + (size_t)m * N_NODES + n0 + tx * 4) =
          make_float4(acc[i2][i][0], acc[i2][i][1], acc[i2][i][2], acc[i2][i][3]);
    }
}

__global__ __launch_bounds__(256) void bias_inplace_kernel(float* __restrict__ P,
                                                           const float* __restrict__ bias) {
  const size_t base = ((size_t)blockIdx.x * 256 + threadIdx.x) * 4;
  const int n = (int)(base & (N_NODES - 1));
  float4 s = *(const float4*)(P + base);
  const float4 bv = *(const float4*)(bias + n);
  s.x += bv.x; s.y += bv.y; s.z += bv.z; s.w += bv.w;
  *(float4*)(P + base) = s;
}

// ---------------------------------------------------------------------------
// Avalanche: one workgroup per sample; state in registers.
// ---------------------------------------------------------------------------
template <int MODE, int NSPLIT>
__global__ __launch_bounds__(1024) void avalanche_kernel(const float* __restrict__ Pin,
                                                         const float* __restrict__ bias,
                                                         const void* __restrict__ connv,
                                                         float* __restrict__ out,
                                                         unsigned int* __restrict__ maxslot) {
  const int b = blockIdx.x;
  const int t = threadIdx.x;
  __shared__ unsigned long long mask[64];
  __shared__ int wincl[64];
  __shared__ int list[N_NODES];

  float4 s;
  if (MODE == 1) {
    const float4 bv = *(const float4*)(bias + t * 4);
    s = bv;
#pragma unroll
    for (int sp = 0; sp < NSPLIT; ++sp) {
      const float4 v = *(const float4*)(Pin + (size_t)sp * BATCH * N_NODES +
                                        (size_t)b * N_NODES + t * 4);
      s.x += v.x; s.y += v.y; s.z += v.z; s.w += v.w;
    }
  } else {
    s = *(const float4*)(Pin + (size_t)b * N_NODES + t * 4);
  }

  float total = 0.0f;

  for (int it = 0; it < 100; ++it) {
    const float v0 = s.x, v1 = s.y, v2 = s.z, v3 = s.w;
    unsigned int bits = 0;
    if (v0 > 1.0f) bits |= 1u;
    if (v1 > 1.0f) bits |= 2u;
    if (v2 > 1.0f) bits |= 4u;
    if (v3 > 1.0f) bits |= 8u;

    __syncthreads();
    if (t < 64) mask[t] = 0ULL;
    __syncthreads();
    if (bits) atomicOr(&mask[t >> 4], (unsigned long long)bits << ((t & 15) * 4));
    __syncthreads();

    if (t < 64) {
      int incl = __popcll(mask[t]);
#pragma unroll
      for (int d = 1; d < 64; d <<= 1) {
        const int y = __shfl_up(incl, d);
        if (t >= d) incl += y;
      }
      wincl[t] = incl;
    }
    __syncthreads();
    const int n = wincl[63];
    if (n == 0) break;  // sticky done: state frozen
    total += (float)n;

    if (t < 64) {
      unsigned long long m = mask[t];
      int o = wincl[t] - __popcll(m);
      while (m) {
        list[o++] = (t << 6) + __builtin_ctzll(m);
        m &= m - 1;
      }
    }
    __syncthreads();

    float4 a0 = make_float4(0.f, 0.f, 0.f, 0.f), a1 = a0, a2 = a0, a3 = a0;
    if (MODE == 1) {
      int idx = 0;
      for (; idx + 8 <= n; idx += 8) {
        const float4 c0 = conn_load4(connv, list[idx + 0], t);
        const float4 c1 = conn_load4(connv, list[idx + 1], t);
        const float4 c2 = conn_load4(connv, list[idx + 2], t);
        const float4 c3 = conn_load4(connv, list[idx + 3], t);
        const float4 c4 = conn_load4(connv, list[idx + 4], t);
        const float4 c5 = conn_load4(connv, list[idx + 5], t);
        const float4 c6 = conn_load4(connv, list[idx + 6], t);
        const float4 c7 = conn_load4(connv, list[idx + 7], t);
        a0.x += c0.x; a0.y += c0.y; a0.z += c0.z; a0.w += c0.w;
        a1.x += c1.x; a1.y += c1.y; a1.z += c1.z; a1.w += c1.w;
        a2.x += c2.x; a2.y += c2.y; a2.z += c2.z; a2.w += c2.w;
        a3.x += c3.x; a3.y += c3.y; a3.z += c3.z; a3.w += c3.w;
        a0.x += c4.x; a0.y += c4.y; a0.z += c4.z; a0.w += c4.w;
        a1.x += c5.x; a1.y += c5.y; a1.z += c5.z; a1.w += c5.w;
        a2.x += c6.x; a2.y += c6.y; a2.z += c6.z; a2.w += c6.w;
        a3.x += c7.x; a3.y += c7.y; a3.z += c7.z; a3.w += c7.w;
      }
      for (; idx < n; ++idx) {
        const float4 c = conn_load4(connv, list[idx], t);
        a0.x += c.x; a0.y += c.y; a0.z += c.z; a0.w += c.w;
      }
    } else {
      const float* conn = (const float*)connv;
      for (int idx = 0; idx < n; ++idx) {
        const int j = list[idx];
        a0.x += conn[(size_t)(t * 4 + 0) * N_NODES + j];
        a0.y += conn[(size_t)(t * 4 + 1) * N_NODES + j];
        a0.z += conn[(size_t)(t * 4 + 2) * N_NODES + j];
        a0.w += conn[(size_t)(t * 4 + 3) * N_NODES + j];
      }
    }
    const float sc = (MODE == 1) ? CONN_SCALE : 1.0f;
    const float4 acc = make_float4(((a0.x + a1.x) + (a2.x + a3.x)) * sc,
                                   ((a0.y + a1.y) + (a2.y + a3.y)) * sc,
                                   ((a0.z + a1.z) + (a2.z + a3.z)) * sc,
                                   ((a0.w + a1.w) + (a2.w + a3.w)) * sc);

    s.x = (v0 > 1.0f) ? 0.0f : 0.9f * v0 + acc.x;
    s.y = (v1 > 1.0f) ? 0.0f : 0.9f * v1 + acc.y;
    s.z = (v2 > 1.0f) ? 0.0f : 0.9f * v2 + acc.z;
    s.w = (v3 > 1.0f) ? 0.0f : 0.9f * v3 + acc.w;
  }

  *(float4*)(out + (size_t)b * N_NODES + t * 4) = s;
  if (t == 0) atomicMax(maxslot, __float_as_uint(total));  // totals >= 0
}

// ---------------------------------------------------------------------------
extern "C" void kernel_launch(void* const* d_in, const int* in_sizes, int n_in,
                              void* d_out, int out_size, void* d_ws, size_t ws_size,
                              hipStream_t stream) {
  const float* input = (const float*)d_in[0];  // [128,4096]
  const float* W     = (const float*)d_in[1];  // [4096,4096]
  const float* bias  = (const float*)d_in[2];  // [4096]
  const float* conn  = (const float*)d_in[3];  // [4096,4096]
  float* out = (float*)d_out;                  // [128*4096] state + [1] max_size

  const size_t aplane_bytes = (size_t)BATCH * N_NODES * 2;                       // 1 MB each
  const size_t connT_bytes  = (size_t)N_NODES * N_NODES * CONN_ELEM_BYTES;       // 16/32 MB
  const size_t part_bytes   = (size_t)SPLITK * BATCH * N_NODES * sizeof(float);  // 16 MB
  unsigned int* maxslot = (unsigned int*)(out + (size_t)BATCH * N_NODES);

  if (ws_size >= 2 * aplane_bytes + connT_bytes + part_bytes) {
    _Float16* Ah = (_Float16*)d_ws;
    _Float16* Al = (_Float16*)((char*)d_ws + aplane_bytes);
    void* connT  = (char*)d_ws + 2 * aplane_bytes;
    float* part  = (float*)((char*)d_ws + 2 * aplane_bytes + connT_bytes);
    asplit_kernel<<<BATCH * N_NODES / 1024, 256, 0, stream>>>(input, Ah, Al, maxslot);
    fused_prep_kernel<<<GEMM_BLOCKS + TRANS_BLOCKS, 256, 0, stream>>>(Ah, Al, W, conn, part,
                                                                      connT);
    avalanche_kernel<1, SPLITK><<<BATCH, 1024, 0, stream>>>(part, bias, connT, out, maxslot);
  } else {
    // Fallback: no workspace — f32 GEMM into d_out, in-place bias, strided gather.
    proj_gemm_valu<<<dim3(N_NODES / 64, 1), 256, 0, stream>>>(input, W, out, maxslot);
    bias_inplace_kernel<<<BATCH * N_NODES / 1024, 256, 0, stream>>>(out, bias);
    avalanche_kernel<0, 1><<<BATCH, 1024, 0, stream>>>(out, nullptr, conn, out, maxslot);
  }
}

// Round 11
// 69.503 us; speedup vs baseline: 1.3583x; 1.0096x over previous
//
#include <hip/hip_runtime.h>

#define N_NODES 4096
#define BATCH 128
#define SPLITK 16
#define GBN 128                    // GEMM N-tile
#define GBK 32                     // GEMM K-step
#define KCHUNK (N_NODES / SPLITK)  // 256
#define NSTEP (KCHUNK / GBK)       // 8
#define GEMM_BLOCKS ((N_NODES / GBN) * SPLITK)  // 512
#define TRANS_BLOCKS 1024                       // 4 tiles/block, 1 wave/tile

typedef _Float16 f16x4 __attribute__((ext_vector_type(4)));
typedef _Float16 f16x8 __attribute__((ext_vector_type(8)));
typedef float f32x4 __attribute__((ext_vector_type(4)));
typedef unsigned int u32x4 __attribute__((ext_vector_type(4)));

// ---- async global->LDS DMA (dest = wave-uniform base + lane*16) ----
__device__ __forceinline__ void dma16(const void* g, void* l) {
#if defined(__has_builtin) && __has_builtin(__builtin_amdgcn_global_load_lds)
  __builtin_amdgcn_global_load_lds((const __attribute__((address_space(1))) void*)g,
                                   (__attribute__((address_space(3))) void*)l, 16, 0, 0);
#else
  *(u32x4*)l = *(const u32x4*)g;
#endif
}

// fp8 connT if the HW cvt builtins exist; else bf16 connT.
#if defined(__has_builtin)
#if __has_builtin(__builtin_amdgcn_cvt_f32_fp8) && __has_builtin(__builtin_amdgcn_cvt_pk_fp8_f32)
#define CONN_FP8 1
#endif
#endif
#ifndef CONN_FP8
#define CONN_FP8 0
#endif

#if CONN_FP8
#define CONN_ELEM_BYTES 1
#define CONN_SCALE (1.0f / 256.0f)
#else
#define CONN_ELEM_BYTES 2
#define CONN_SCALE 1.0f
#endif

__device__ __forceinline__ void conn_store4(void* out, size_t off, float4 v) {
#if CONN_FP8
  unsigned int p = __builtin_amdgcn_cvt_pk_fp8_f32(v.x * 256.0f, v.y * 256.0f, 0, false);
  p = (unsigned int)__builtin_amdgcn_cvt_pk_fp8_f32(v.z * 256.0f, v.w * 256.0f, (int)p, true);
  *(unsigned int*)((unsigned char*)out + off) = p;
#else
  const unsigned int ux = __float_as_uint(v.x), uy = __float_as_uint(v.y);
  const unsigned int uz = __float_as_uint(v.z), uw = __float_as_uint(v.w);
  ushort4 u;
  u.x = (unsigned short)((ux + 0x7FFFu + ((ux >> 16) & 1u)) >> 16);  // RNE
  u.y = (unsigned short)((uy + 0x7FFFu + ((uy >> 16) & 1u)) >> 16);
  u.z = (unsigned short)((uz + 0x7FFFu + ((uz >> 16) & 1u)) >> 16);
  u.w = (unsigned short)((uw + 0x7FFFu + ((uw >> 16) & 1u)) >> 16);
  *(ushort4*)((unsigned short*)out + off) = u;
#endif
}

__device__ __forceinline__ float4 conn_load4(const void* cT, int j, int t) {
#if CONN_FP8
  const unsigned int c = *(const unsigned int*)((const unsigned char*)cT + ((size_t)j << 12) + t * 4);
  return make_float4(__builtin_amdgcn_cvt_f32_fp8(c, 0), __builtin_amdgcn_cvt_f32_fp8(c, 1),
                     __builtin_amdgcn_cvt_f32_fp8(c, 2), __builtin_amdgcn_cvt_f32_fp8(c, 3));
#else
  const ushort4 c = *(const ushort4*)((const unsigned short*)cT + ((size_t)j << 12) + t * 4);
  return make_float4(__uint_as_float((unsigned int)c.x << 16),
                     __uint_as_float((unsigned int)c.y << 16),
                     __uint_as_float((unsigned int)c.z << 16),
                     __uint_as_float((unsigned int)c.w << 16));
#endif
}

// ---------------------------------------------------------------------------
// A-split, interleaved: per row m, per 32-k group: (hi[32] | lo[32]) f16,
// pre-scaled x256. Row = 8192 f16 = 16 KB. Also zeroes maxslot.
// ---------------------------------------------------------------------------
__global__ __launch_bounds__(256) void asplit_kernel(const float* __restrict__ in,
                                                     _Float16* __restrict__ As,
                                                     unsigned int* __restrict__ maxslot) {
  if (blockIdx.x == 0 && threadIdx.x == 0) *maxslot = 0u;
  const size_t idx = ((size_t)blockIdx.x * 256 + threadIdx.x) * 4;
  const int m = (int)(idx >> 12);
  const int k = (int)(idx & (N_NODES - 1));
  const float4 v = *(const float4*)(in + idx);
  f16x4 hi, lo;
  const float x0 = v.x * 256.f, x1 = v.y * 256.f, x2 = v.z * 256.f, x3 = v.w * 256.f;
  hi[0] = (_Float16)x0; lo[0] = (_Float16)(x0 - (float)hi[0]);
  hi[1] = (_Float16)x1; lo[1] = (_Float16)(x1 - (float)hi[1]);
  hi[2] = (_Float16)x2; lo[2] = (_Float16)(x2 - (float)hi[2]);
  hi[3] = (_Float16)x3; lo[3] = (_Float16)(x3 - (float)hi[3]);
  const size_t base = (size_t)m * 8192 + (size_t)(k >> 5) * 64 + (k & 31);
  *(f16x4*)(As + base) = hi;
  *(f16x4*)(As + base + 32) = lo;
}

// ---------------------------------------------------------------------------
// Fused prep. Blocks [0,512): 128x128-tile split-f16 MFMA GEMM, splitK=16 —
// LDS dbuf + global_load_lds DMA + counted vmcnt + both-sides XOR swizzle
// (granule ^= row&7 within 128B rows -> frag reads 2-way banked = free).
// Blocks [512,1536): per-wave barrier-free transpose, 4 tiles/block.
// ---------------------------------------------------------------------------
struct GemmSmem {
  alignas(16) _Float16 A[2][128 * 64];  // 2 x 16 KB (hi32|lo32 interleaved rows)
  alignas(16) float B[2][128 * 32];     // 2 x 16 KB (f32 rows)
};  // 64 KB
struct TransSmem { float tile[4][64][65]; };  // 66.6 KB
union PrepSmem { GemmSmem g; TransSmem t; };

__global__ __launch_bounds__(256, 2) void fused_prep_kernel(
    const _Float16* __restrict__ As, const float* __restrict__ W,
    const float* __restrict__ conn, float* __restrict__ P, void* __restrict__ connT) {
  __shared__ PrepSmem sm;
  const int tid = threadIdx.x;
  const int bid = blockIdx.x;
  const int wave = tid >> 6, lane = tid & 63;

  if (bid < GEMM_BLOCKS) {
    // ---------------- GEMM role ----------------
    const int wm = wave >> 1, wn = wave & 1;    // 2x2 wave grid, 64x64 each
    const int g = lane >> 4, lrow = lane & 15;  // frag lane coords
    const int n0 = (bid & 31) * GBN;
    const int kb = (bid >> 5) * KCHUNK;
    const int crow = lane >> 3;  // row within 8-row chunk (== row&7)
    const int q = lane & 7;      // 16B granule within 128B row

    // 8 DMAs per wave per issue: 4 A-chunks + 4 B-chunks (1 KB each).
    auto issue = [&](int buf, int t) {
      const size_t abyte = (size_t)((kb >> 5) + t) * 128;          // A row: 16KB, 128B/group
      const size_t bbyte = (size_t)(kb + t * GBK) * 4;             // W row: 16KB f32
#pragma unroll
      for (int i = 0; i < 4; ++i) {
        const int c = wave * 4 + i;      // 0..15
        const int row = c * 8 + crow;    // 0..127
        dma16((const char*)As + (size_t)row * 16384 + abyte + ((q ^ crow) << 4),
              (char*)sm.g.A[buf] + c * 1024 + lane * 16);
      }
#pragma unroll
      for (int i = 0; i < 4; ++i) {
        const int c = wave * 4 + i;
        const int row = c * 8 + crow;
        dma16((const char*)W + (size_t)(n0 + row) * 16384 + bbyte + ((q ^ crow) << 4),
              (char*)sm.g.B[buf] + c * 1024 + lane * 16);
      }
    };

    f32x4 acc[4][4] = {};
    issue(0, 0);
    issue(1, 1);

#pragma unroll
    for (int t = 0; t < NSTEP; ++t) {
      const int cur = t & 1;
      // Counted drain: tile t landed; tile t+1's 8 DMAs stay in flight.
      if (t + 1 < NSTEP) asm volatile("s_waitcnt vmcnt(8)" ::: "memory");
      else               asm volatile("s_waitcnt vmcnt(0)" ::: "memory");
      __builtin_amdgcn_sched_barrier(0);
      __builtin_amdgcn_s_barrier();
      __builtin_amdgcn_sched_barrier(0);

      // A frags: granule g = hi k[g*8..+8), granule 4+g = lo
      f16x8 ah[4], al[4];
#pragma unroll
      for (int fm = 0; fm < 4; ++fm) {
        const int mr = wm * 64 + fm * 16 + lrow;
        const char* ab = (const char*)sm.g.A[cur] + mr * 128;
        const int s = (mr & 7) << 4;
        ah[fm] = *(const f16x8*)(ab + ((g << 4) ^ s));
        al[fm] = *(const f16x8*)(ab + (((4 + g) << 4) ^ s));
      }
      // B frags: 8 f32 at granules 2g,2g+1 -> consumer-side hi/lo split (x64)
      f16x8 bh[4], bl[4];
#pragma unroll
      for (int fn = 0; fn < 4; ++fn) {
        const int nr = wn * 64 + fn * 16 + lrow;
        const char* bb = (const char*)sm.g.B[cur] + nr * 128;
        const int s = (nr & 7) << 4;
        const f32x4 b0 = *(const f32x4*)(bb + (((2 * g) << 4) ^ s));
        const f32x4 b1 = *(const f32x4*)(bb + (((2 * g + 1) << 4) ^ s));
#pragma unroll
        for (int j = 0; j < 4; ++j) {
          const float x = b0[j] * 64.f;
          const _Float16 h = (_Float16)x;
          bh[fn][j] = h; bl[fn][j] = (_Float16)(x - (float)h);
          const float y = b1[j] * 64.f;
          const _Float16 h2 = (_Float16)y;
          bh[fn][4 + j] = h2; bl[fn][4 + j] = (_Float16)(y - (float)h2);
        }
      }
#pragma unroll
      for (int fm = 0; fm < 4; ++fm)
#pragma unroll
        for (int fn = 0; fn < 4; ++fn) {
          acc[fm][fn] = __builtin_amdgcn_mfma_f32_16x16x32_f16(ah[fm], bh[fn], acc[fm][fn], 0, 0, 0);
          acc[fm][fn] = __builtin_amdgcn_mfma_f32_16x16x32_f16(ah[fm], bl[fn], acc[fm][fn], 0, 0, 0);
          acc[fm][fn] = __builtin_amdgcn_mfma_f32_16x16x32_f16(al[fm], bh[fn], acc[fm][fn], 0, 0, 0);
        }

      __builtin_amdgcn_sched_barrier(0);
      __builtin_amdgcn_s_barrier();  // all waves done reading buf cur
      __builtin_amdgcn_sched_barrier(0);
      if (t + 2 < NSTEP) issue(cur, t + 2);
    }

    // epilogue: D row = (lane>>4)*4 + reg, col = lane&15 (HW-verified)
    constexpr float INV = 1.0f / 16384.0f;  // 1/(256*64)
    float* Pb = P + (size_t)(bid >> 5) * BATCH * N_NODES;
#pragma unroll
    for (int fm = 0; fm < 4; ++fm)
#pragma unroll
      for (int fn = 0; fn < 4; ++fn) {
        const int n = n0 + wn * 64 + fn * 16 + lrow;
#pragma unroll
        for (int reg = 0; reg < 4; ++reg) {
          const int m = wm * 64 + fm * 16 + g * 4 + reg;
          Pb[(size_t)m * N_NODES + n] = acc[fm][fn][reg] * INV;
        }
      }
  } else {
    // -------- transpose role: per-wave, barrier-free, 4 tiles/block --------
    const int tile_id = (bid - GEMM_BLOCKS) * 4 + wave;  // 0..4095
    const int bx = tile_id & 63, by = tile_id >> 6;
    float (*T)[65] = sm.t.tile[wave];
    const int lr = lane >> 4;  // 0..3
    const int lc = lane & 15;  // 0..15
#pragma unroll
    for (int i = 0; i < 16; ++i) {
      const int r = lr + 4 * i;
      const float4 v = *(const float4*)(conn + (size_t)(by * 64 + r) * N_NODES + bx * 64 + lc * 4);
      T[r][lc * 4 + 0] = v.x; T[r][lc * 4 + 1] = v.y;
      T[r][lc * 4 + 2] = v.z; T[r][lc * 4 + 3] = v.w;
    }
#pragma unroll
    for (int i = 0; i < 16; ++i) {
      const int orow = lr + 4 * i;
      float4 v;
      v.x = T[lc * 4 + 0][orow];
      v.y = T[lc * 4 + 1][orow];
      v.z = T[lc * 4 + 2][orow];
      v.w = T[lc * 4 + 3][orow];
      conn_store4(connT, (size_t)(bx * 64 + orow) * N_NODES + by * 64 + lc * 4, v);
    }
  }
}

// ---------------------------------------------------------------------------
// Fallback-only f32 VALU GEMM (no workspace)
// ---------------------------------------------------------------------------
__global__ __launch_bounds__(256) void proj_gemm_valu(const float* __restrict__ A,
                                                      const float* __restrict__ W,
                                                      float* __restrict__ P,
                                                      unsigned int* __restrict__ maxslot) {
  if (blockIdx.x == 0 && threadIdx.x == 0) *maxslot = 0u;
  __shared__ float Asb[16][132];
  __shared__ float Bsb[16][68];
  const int tid = threadIdx.x;
  const int n0 = blockIdx.x * 64;
  const int tx = tid & 15, ty = tid >> 4;
  const int arow = tid >> 1, acol = (tid & 1) * 8;
  const int brow = tid >> 2, bcol = (tid & 3) * 4;
  float acc[2][4][4] = {};
  const float* Aptr = A + (size_t)arow * N_NODES + acol;
  const float* Wptr = W + (size_t)(n0 + brow) * N_NODES + bcol;
  for (int k0 = 0; k0 < N_NODES; k0 += 16) {
    const float4 a0 = *(const float4*)(Aptr + k0);
    const float4 a1 = *(const float4*)(Aptr + k0 + 4);
    const float4 bv = *(const float4*)(Wptr + k0);
    __syncthreads();
    Asb[acol + 0][arow] = a0.x; Asb[acol + 1][arow] = a0.y;
    Asb[acol + 2][arow] = a0.z; Asb[acol + 3][arow] = a0.w;
    Asb[acol + 4][arow] = a1.x; Asb[acol + 5][arow] = a1.y;
    Asb[acol + 6][arow] = a1.z; Asb[acol + 7][arow] = a1.w;
    Bsb[bcol + 0][brow] = bv.x; Bsb[bcol + 1][brow] = bv.y;
    Bsb[bcol + 2][brow] = bv.z; Bsb[bcol + 3][brow] = bv.w;
    __syncthreads();
#pragma unroll
    for (int kk = 0; kk < 16; ++kk) {
      const float4 av0 = *(const float4*)&Asb[kk][ty * 4];
      const float4 av1 = *(const float4*)&Asb[kk][64 + ty * 4];
      const float4 bv4 = *(const float4*)&Bsb[kk][tx * 4];
      const float am[8] = {av0.x, av0.y, av0.z, av0.w, av1.x, av1.y, av1.z, av1.w};
      const float bn[4] = {bv4.x, bv4.y, bv4.z, bv4.w};
#pragma unroll
      for (int i2 = 0; i2 < 2; ++i2)
#pragma unroll
        for (int i = 0; i < 4; ++i)
#pragma unroll
          for (int j = 0; j < 4; ++j)
            acc[i2][i][j] += am[i2 * 4 + i] * bn[j];
    }
  }
#pragma unroll
  for (int i2 = 0; i2 < 2; ++i2)
#pragma unroll
    for (int i = 0; i < 4; ++i) {
      const int m = i2 * 64 + ty * 4 + i;
      *(float4*)(P + (size_t)m * N_NODES + n0 + tx * 4) =
          make_float4(acc[i2][i][0], acc[i2][i][1], acc[i2][i][2], acc[i2][i][3]);
    }
}

__global__ __launch_bounds__(256) void bias_inplace_kernel(float* __restrict__ P,
                                                           const float* __restrict__ bias) {
  const size_t base = ((size_t)blockIdx.x * 256 + threadIdx.x) * 4;
  const int n = (int)(base & (N_NODES - 1));
  float4 s = *(const float4*)(P + base);
  const float4 bv = *(const float4*)(bias + n);
  s.x += bv.x; s.y += bv.y; s.z += bv.z; s.w += bv.w;
  *(float4*)(P + base) = s;
}

// ---------------------------------------------------------------------------
// Avalanche: one workgroup per sample; state in registers.
// ---------------------------------------------------------------------------
template <int MODE, int NSPLIT>
__global__ __launch_bounds__(1024) void avalanche_kernel(const float* __restrict__ Pin,
                                                         const float* __restrict__ bias,
                                                         const void* __restrict__ connv,
                                                         float* __restrict__ out,
                                                         unsigned int* __restrict__ maxslot) {
  const int b = blockIdx.x;
  const int t = threadIdx.x;
  __shared__ unsigned long long mask[64];
  __shared__ int wincl[64];
  __shared__ int list[N_NODES];

  float4 s;
  if (MODE == 1) {
    const float4 bv = *(const float4*)(bias + t * 4);
    s = bv;
#pragma unroll
    for (int sp = 0; sp < NSPLIT; ++sp) {
      const float4 v = *(const float4*)(Pin + (size_t)sp * BATCH * N_NODES +
                                        (size_t)b * N_NODES + t * 4);
      s.x += v.x; s.y += v.y; s.z += v.z; s.w += v.w;
    }
  } else {
    s = *(const float4*)(Pin + (size_t)b * N_NODES + t * 4);
  }

  float total = 0.0f;

  for (int it = 0; it < 100; ++it) {
    const float v0 = s.x, v1 = s.y, v2 = s.z, v3 = s.w;
    unsigned int bits = 0;
    if (v0 > 1.0f) bits |= 1u;
    if (v1 > 1.0f) bits |= 2u;
    if (v2 > 1.0f) bits |= 4u;
    if (v3 > 1.0f) bits |= 8u;

    __syncthreads();
    if (t < 64) mask[t] = 0ULL;
    __syncthreads();
    if (bits) atomicOr(&mask[t >> 4], (unsigned long long)bits << ((t & 15) * 4));
    __syncthreads();

    if (t < 64) {
      int incl = __popcll(mask[t]);
#pragma unroll
      for (int d = 1; d < 64; d <<= 1) {
        const int y = __shfl_up(incl, d);
        if (t >= d) incl += y;
      }
      wincl[t] = incl;
    }
    __syncthreads();
    const int n = wincl[63];
    if (n == 0) break;  // sticky done: state frozen
    total += (float)n;

    if (t < 64) {
      unsigned long long m = mask[t];
      int o = wincl[t] - __popcll(m);
      while (m) {
        list[o++] = (t << 6) + __builtin_ctzll(m);
        m &= m - 1;
      }
    }
    __syncthreads();

    float4 a0 = make_float4(0.f, 0.f, 0.f, 0.f), a1 = a0, a2 = a0, a3 = a0;
    if (MODE == 1) {
      int idx = 0;
      for (; idx + 8 <= n; idx += 8) {
        const float4 c0 = conn_load4(connv, list[idx + 0], t);
        const float4 c1 = conn_load4(connv, list[idx + 1], t);
        const float4 c2 = conn_load4(connv, list[idx + 2], t);
        const float4 c3 = conn_load4(connv, list[idx + 3], t);
        const float4 c4 = conn_load4(connv, list[idx + 4], t);
        const float4 c5 = conn_load4(connv, list[idx + 5], t);
        const float4 c6 = conn_load4(connv, list[idx + 6], t);
        const float4 c7 = conn_load4(connv, list[idx + 7], t);
        a0.x += c0.x; a0.y += c0.y; a0.z += c0.z; a0.w += c0.w;
        a1.x += c1.x; a1.y += c1.y; a1.z += c1.z; a1.w += c1.w;
        a2.x += c2.x; a2.y += c2.y; a2.z += c2.z; a2.w += c2.w;
        a3.x += c3.x; a3.y += c3.y; a3.z += c3.z; a3.w += c3.w;
        a0.x += c4.x; a0.y += c4.y; a0.z += c4.z; a0.w += c4.w;
        a1.x += c5.x; a1.y += c5.y; a1.z += c5.z; a1.w += c5.w;
        a2.x += c6.x; a2.y += c6.y; a2.z += c6.z; a2.w += c6.w;
        a3.x += c7.x; a3.y += c7.y; a3.z += c7.z; a3.w += c7.w;
      }
      for (; idx < n; ++idx) {
        const float4 c = conn_load4(connv, list[idx], t);
        a0.x += c.x; a0.y += c.y; a0.z += c.z; a0.w += c.w;
      }
    } else {
      const float* conn = (const float*)connv;
      for (int idx = 0; idx < n; ++idx) {
        const int j = list[idx];
        a0.x += conn[(size_t)(t * 4 + 0) * N_NODES + j];
        a0.y += conn[(size_t)(t * 4 + 1) * N_NODES + j];
        a0.z += conn[(size_t)(t * 4 + 2) * N_NODES + j];
        a0.w += conn[(size_t)(t * 4 + 3) * N_NODES + j];
      }
    }
    const float sc = (MODE == 1) ? CONN_SCALE : 1.0f;
    const float4 acc = make_float4(((a0.x + a1.x) + (a2.x + a3.x)) * sc,
                                   ((a0.y + a1.y) + (a2.y + a3.y)) * sc,
                                   ((a0.z + a1.z) + (a2.z + a3.z)) * sc,
                                   ((a0.w + a1.w) + (a2.w + a3.w)) * sc);

    s.x = (v0 > 1.0f) ? 0.0f : 0.9f * v0 + acc.x;
    s.y = (v1 > 1.0f) ? 0.0f : 0.9f * v1 + acc.y;
    s.z = (v2 > 1.0f) ? 0.0f : 0.9f * v2 + acc.z;
    s.w = (v3 > 1.0f) ? 0.0f : 0.9f * v3 + acc.w;
  }

  *(float4*)(out + (size_t)b * N_NODES + t * 4) = s;
  if (t == 0) atomicMax(maxslot, __float_as_uint(total));  // totals >= 0
}

// ---------------------------------------------------------------------------
extern "C" void kernel_launch(void* const* d_in, const int* in_sizes, int n_in,
                              void* d_out, int out_size, void* d_ws, size_t ws_size,
                              hipStream_t stream) {
  const float* input = (const float*)d_in[0];  // [128,4096]
  const float* W     = (const float*)d_in[1];  // [4096,4096]
  const float* bias  = (const float*)d_in[2];  // [4096]
  const float* conn  = (const float*)d_in[3];  // [4096,4096]
  float* out = (float*)d_out;                  // [128*4096] state + [1] max_size

  const size_t aplane_bytes = (size_t)BATCH * N_NODES * 4;                       // 2 MB interleaved
  const size_t connT_bytes  = (size_t)N_NODES * N_NODES * CONN_ELEM_BYTES;       // 16/32 MB
  const size_t part_bytes   = (size_t)SPLITK * BATCH * N_NODES * sizeof(float);  // 32 MB
  unsigned int* maxslot = (unsigned int*)(out + (size_t)BATCH * N_NODES);

  if (ws_size >= aplane_bytes + connT_bytes + part_bytes) {
    _Float16* As = (_Float16*)d_ws;
    void* connT  = (char*)d_ws + aplane_bytes;
    float* part  = (float*)((char*)d_ws + aplane_bytes + connT_bytes);
    asplit_kernel<<<BATCH * N_NODES / 1024, 256, 0, stream>>>(input, As, maxslot);
    fused_prep_kernel<<<GEMM_BLOCKS + TRANS_BLOCKS, 256, 0, stream>>>(As, W, conn, part, connT);
    avalanche_kernel<1, SPLITK><<<BATCH, 1024, 0, stream>>>(part, bias, connT, out, maxslot);
  } else {
    // Fallback: no workspace — f32 GEMM into d_out, in-place bias, strided gather.
    proj_gemm_valu<<<dim3(N_NODES / 64, 1), 256, 0, stream>>>(input, W, out, maxslot);
    bias_inplace_kernel<<<BATCH * N_NODES / 1024, 256, 0, stream>>>(out, bias);
    avalanche_kernel<0, 1><<<BATCH, 1024, 0, stream>>>(out, nullptr, conn, out, maxslot);
  }
}